// Round 5
// baseline (116.742 us; speedup 1.0000x reference)
//
#include <hip/hip_runtime.h>
#include <hip/hip_fp16.h>

// PointSpatialTransformer: bilinear gather of normalized-flow field at 4M points.
// H = W = 512.
// Round-5 design (MLP-focused):
//  * 2 MB row-pair table P[512][512] (uint2): P[i][j] = {half2(Lx,Ly)[i][j], [i][j+1]}
//    -> bilinear needs TWO aligned 8B gathers (row x0 and row x0+1).
//  * pst kernel: 4 points/thread straight-line, so 2 point loads + 8 gathers are
//    all in flight before any waitcnt -> ~10 outstanding VMEM ops/wave
//    (round-4 had ~2; kernel was latency-bound at 1.4 TB/s with all pipes idle).
//  * nontemporal only on stores (keep points/table in L2).

constexpr int HH = 512;
constexpr int WW = 512;

typedef float f32x4 __attribute__((ext_vector_type(4)));

__device__ __forceinline__ unsigned int pack_LxLy(const float* __restrict__ flow,
                                                  int i, int j) {
    const float s = 2.0f / 511.0f;
    float lx = fmaf((float)j + flow[(i << 9) + j + HH * WW], s, -1.0f); // ch1
    float ly = fmaf((float)i + flow[(i << 9) + j], s, -1.0f);          // ch0
    __half2 h = __float22half2_rn(make_float2(lx, ly));
    return *reinterpret_cast<unsigned int*>(&h);
}

// ---------------- Kernel 1: build row-pair table (2 MB) ----------------
__global__ __launch_bounds__(256) void build_P_kernel(const float* __restrict__ flow,
                                                      uint2* __restrict__ P) {
    int idx = blockIdx.x * 256 + threadIdx.x;   // 0 .. 262143
    int i = idx >> 9;
    int j = idx & 511;
    int jp = min(j + 1, 511);
    uint2 e;
    e.x = pack_LxLy(flow, i, j);
    e.y = pack_LxLy(flow, i, jp);
    P[idx] = e;
}

__device__ __forceinline__ float2 h2f(unsigned int u) {
    __half2 h = *reinterpret_cast<__half2*>(&u);
    return __half22float2(h);
}

// bilinear combine, reference weight/corner pairing kept verbatim
__device__ __forceinline__ float2 combine(uint2 top, uint2 bot, float xf, float yf) {
    float2 v00 = h2f(top.x);
    float2 v01 = h2f(top.y);
    float2 v10 = h2f(bot.x);
    float2 v11 = h2f(bot.y);
    float w00 = xf * yf;
    float w10 = xf * (1.0f - yf);
    float w01 = (1.0f - xf) * yf;
    float w11 = (1.0f - xf) * (1.0f - yf);
    float tx = w00 * v00.x + w10 * v10.x + w01 * v01.x + w11 * v11.x;
    float ty = w00 * v00.y + w10 * v10.y + w01 * v01.y + w11 * v11.y;
    // out = ((ty+1)*256, (tx+1)*256)
    return make_float2((ty + 1.0f) * 256.0f, (tx + 1.0f) * 256.0f);
}

__device__ __forceinline__ float2 point_scalar(const uint2* __restrict__ P,
                                               float x, float y, bool bil) {
    if (bil) {
        float xt = truncf(x), yt = truncf(y);
        int x0 = (int)xt, y0 = (int)yt;
        uint2 top = P[(x0 << 9) + y0];
        uint2 bot = P[((x0 + 1) << 9) + y0];
        return combine(top, bot, x - xt, y - yt);
    } else {
        int xi = min((int)rintf(x), 511);
        int yi = min((int)rintf(y), 511);
        float2 t = h2f(P[(xi << 9) + yi].x);
        return make_float2((t.y + 1.0f) * 256.0f, (t.x + 1.0f) * 256.0f);
    }
}

// ---------------- Kernel 2: 4 points/thread, straight-line ----------------
__global__ __launch_bounds__(256) void pst_kernel(const float* __restrict__ point,
                                                  const uint2* __restrict__ P,
                                                  const int* __restrict__ intep,
                                                  float* __restrict__ out,
                                                  int n /* number of points */) {
    const bool bil = (*intep != 0);
    int tid = blockIdx.x * 256 + threadIdx.x;
    int base = tid * 4;                       // first point this thread owns

    if (base + 3 < n) {
        const f32x4* pts = reinterpret_cast<const f32x4*>(point);
        f32x4* out4 = reinterpret_cast<f32x4*>(out);
        // two independent 16B loads (points 4t..4t+3)
        f32x4 pA = pts[tid * 2];
        f32x4 pB = pts[tid * 2 + 1];

        if (bil) {
            float x[4] = {pA.x, pA.z, pB.x, pB.z};
            float y[4] = {pA.y, pA.w, pB.y, pB.w};
            float xt[4], yt[4], xf[4], yf[4];
            int idx_top[4], idx_bot[4];
#pragma unroll
            for (int k = 0; k < 4; ++k) {
                xt[k] = truncf(x[k]); yt[k] = truncf(y[k]);
                xf[k] = x[k] - xt[k]; yf[k] = y[k] - yt[k];
                int x0 = (int)xt[k], y0 = (int)yt[k];
                idx_top[k] = (x0 << 9) + y0;
                idx_bot[k] = idx_top[k] + 512;
            }
            // issue all 8 gathers before consuming any
            uint2 top[4], bot[4];
#pragma unroll
            for (int k = 0; k < 4; ++k) { top[k] = P[idx_top[k]]; bot[k] = P[idx_bot[k]]; }

            float2 r0 = combine(top[0], bot[0], xf[0], yf[0]);
            float2 r1 = combine(top[1], bot[1], xf[1], yf[1]);
            float2 r2 = combine(top[2], bot[2], xf[2], yf[2]);
            float2 r3 = combine(top[3], bot[3], xf[3], yf[3]);
            f32x4 oA = {r0.x, r0.y, r1.x, r1.y};
            f32x4 oB = {r2.x, r2.y, r3.x, r3.y};
            __builtin_nontemporal_store(oA, &out4[tid * 2]);
            __builtin_nontemporal_store(oB, &out4[tid * 2 + 1]);
        } else {
            float x[4] = {pA.x, pA.z, pB.x, pB.z};
            float y[4] = {pA.y, pA.w, pB.y, pB.w};
            unsigned int v[4];
#pragma unroll
            for (int k = 0; k < 4; ++k) {
                int xi = min((int)rintf(x[k]), 511);
                int yi = min((int)rintf(y[k]), 511);
                v[k] = P[(xi << 9) + yi].x;
            }
            float2 t0 = h2f(v[0]), t1 = h2f(v[1]), t2 = h2f(v[2]), t3 = h2f(v[3]);
            f32x4 oA = {(t0.y + 1.0f) * 256.0f, (t0.x + 1.0f) * 256.0f,
                        (t1.y + 1.0f) * 256.0f, (t1.x + 1.0f) * 256.0f};
            f32x4 oB = {(t2.y + 1.0f) * 256.0f, (t2.x + 1.0f) * 256.0f,
                        (t3.y + 1.0f) * 256.0f, (t3.x + 1.0f) * 256.0f};
            __builtin_nontemporal_store(oA, &out4[tid * 2]);
            __builtin_nontemporal_store(oB, &out4[tid * 2 + 1]);
        }
    } else if (base < n) {
        // tail: per-point scalar path
        const float2* pt2 = reinterpret_cast<const float2*>(point);
        float2* out2 = reinterpret_cast<float2*>(out);
        for (int k = base; k < n; ++k) {
            float2 p = pt2[k];
            out2[k] = point_scalar(P, p.x, p.y, bil);
        }
    }
}

extern "C" void kernel_launch(void* const* d_in, const int* in_sizes, int n_in,
                              void* d_out, int out_size, void* d_ws, size_t ws_size,
                              hipStream_t stream) {
    const float* point = (const float*)d_in[0];  // (1, N, 2)
    const float* flow  = (const float*)d_in[1];  // (1, 2, 512, 512)
    const int*   intep = (const int*)d_in[2];    // scalar
    float* out = (float*)d_out;                  // (1, N, 2)

    const int n = in_sizes[0] / 2;               // number of points

    uint2* P = (uint2*)d_ws;                     // 2 MB table in workspace

    build_P_kernel<<<HH * WW / 256, 256, 0, stream>>>(flow, P);

    int nthreads = (n + 3) / 4;
    int blocks = (nthreads + 255) / 256;
    if (blocks < 1) blocks = 1;
    pst_kernel<<<blocks, 256, 0, stream>>>(point, P, intep, out, n);
}